// Round 11
// baseline (1494.873 us; speedup 1.0000x reference)
//
#include <hip/hip_runtime.h>
#include <stdint.h>

// N=64, T=128, D=512, H=1024, 4H=4096.
// R16 = R14 (best, 797us) + TAIL-OVERLAPPED halfA STAGING (single change):
//   R15 falsified "phase A is staging-BW-bound" (widening staging hurt);
//   phase A is DETECT-bound. So remove the OTHER serial segment: A-detect
//   + A-stage (~0.9us) moves off the critical path:
//   - After the hpk barrier (B5), waves 4-7 poll A-flags(t+1) and stage
//     halfA(t+1) into hS, CONCURRENT with wave 0's publish. Safe because
//     nobody reads hS between B3 and next phase A, and hpk persists.
//   - Deadlock-free by construction: polls start only after B5 (publish
//     needs only waves 0-3 past B5), and a wg NEVER polls its own flag --
//     its own 8 columns are substituted from hpk (LDS h(t+1)).
//   - Loop top: single barrier (was poll+bar+stage+bar). Barriers 6 -> 5.
//   - Phase A/B duties are R14 verbatim (waves 4,5: scores 0,1 on halfA;
//     waves 6,7: B-poll + stage halfB, then scores 2,3 in phase B).
//   - Prologue stages FULL hS(0) (no flags; k_init precedes).
// Mechanism record: R8 -828us (Wh-in-LDS+cached ring); R11 -143us (diet+
// score rebalance); R14 -71us (split-K pipelining); R15 +43us REVERTED.

#define Tt 128
#define FH 4096
#define RING_D 32

typedef __bf16 bf8 __attribute__((ext_vector_type(8)));
typedef float f4 __attribute__((ext_vector_type(4)));
typedef short s8v __attribute__((ext_vector_type(8)));
typedef unsigned long long ull;

__device__ __forceinline__ float bf2f(unsigned short u) {
    union { unsigned u32; float f; } x; x.u32 = ((unsigned)u) << 16; return x.f;
}
__device__ __forceinline__ unsigned short f2bf(float f) {
    union { float f32; unsigned u; } x; x.f32 = f;
    unsigned r = x.u + 0x7fffu + ((x.u >> 16) & 1u);
    return (unsigned short)(r >> 16);
}
__device__ __forceinline__ ull ald(const ull* p) {
    return __hip_atomic_load((ull*)p, __ATOMIC_RELAXED, __HIP_MEMORY_SCOPE_AGENT);
}
__device__ __forceinline__ void ast(ull* p, ull v) {
    __hip_atomic_store(p, v, __ATOMIC_RELAXED, __HIP_MEMORY_SCOPE_AGENT);
}
__device__ __forceinline__ int aldi(const int* p) {
    return __hip_atomic_load((int*)p, __ATOMIC_RELAXED, __HIP_MEMORY_SCOPE_AGENT);
}
__device__ __forceinline__ void asti(int* p, int v) {
    __hip_atomic_store(p, v, __ATOMIC_RELAXED, __HIP_MEMORY_SCOPE_AGENT);
}

// ---------------- converts / init ----------------

__global__ __launch_bounds__(256) void k_cast_bf16(const float* __restrict__ in,
                                                   unsigned short* __restrict__ out, int n) {
    int i = blockIdx.x * 256 + threadIdx.x;
    if (i < n) out[i] = f2bf(in[i]);
}

__global__ __launch_bounds__(256) void k_transpose_bf16(const float* __restrict__ W,
                                                        unsigned short* __restrict__ WT, int K) {
    __shared__ float tl[32][33];
    int c0 = blockIdx.x * 32, k0 = blockIdx.y * 32;
    int tx = threadIdx.x & 31, ty = threadIdx.x >> 5;
    #pragma unroll
    for (int i = 0; i < 32; i += 8) tl[ty + i][tx] = W[(size_t)(k0 + ty + i) * 4096 + c0 + tx];
    __syncthreads();
    #pragma unroll
    for (int i = 0; i < 32; i += 8) WT[(size_t)(c0 + ty + i) * K + k0 + tx] = f2bf(tl[tx][ty + i]);
}

__global__ __launch_bounds__(256) void k_afl(const float* __restrict__ A,
                                             unsigned short* __restrict__ Afl) {
    int idx = blockIdx.x * 256 + threadIdx.x;
    int k = idx & 1023, l = (idx >> 10) & 15, n = idx >> 14;
    Afl[idx] = f2bf(A[((size_t)n * 1024 + k) * 16 + l]);   // Afl[n][l][k]
}

__global__ __launch_bounds__(256) void k_init(const float* __restrict__ A,
                                              float* __restrict__ cstate,
                                              unsigned short* __restrict__ ring0) {
    int idx = blockIdx.x * 256 + threadIdx.x;   // 64*1024
    const float* ap = A + (size_t)idx * 16;
    float s = 0.f;
    #pragma unroll
    for (int l = 0; l < 16; l++) s += ap[l];
    float h = s * (1.0f / 16.0f);
    cstate[idx] = h;
    ring0[idx] = f2bf(h);
}

// ---------------- generic bf16 MFMA GEMM (preamble) ----------------
// mode 0: out[row][col]
// mode 1: P2 layout [n][j(1024)][gate(4)][l(16)]   (row = n*16 + l)
// mode 2: xwx layout [t][n][j(1024)][gate(4)]      (row = n*128 + t)
__global__ __launch_bounds__(256) void k_gemm(const unsigned short* __restrict__ A,
                                              const unsigned short* __restrict__ BT,
                                              const float* __restrict__ bias,
                                              unsigned short* __restrict__ out,
                                              int M, int Nn, int K, int mode) {
    __shared__ unsigned short As[128][40];
    __shared__ unsigned short Bs[128][40];
    int m0 = blockIdx.y * 128, n0 = blockIdx.x * 128;
    int tid = threadIdx.x, lane = tid & 63, wave = tid >> 6;
    int wr = wave >> 1, wc = wave & 1, quad = lane >> 4, l16 = lane & 15;
    f4 acc[4][4];
    #pragma unroll
    for (int i = 0; i < 4; i++)
        #pragma unroll
        for (int j = 0; j < 4; j++) acc[i][j] = f4{0.f, 0.f, 0.f, 0.f};

    for (int k0 = 0; k0 < K; k0 += 32) {
        __syncthreads();
        #pragma unroll
        for (int i = 0; i < 2; i++) {
            int idx = i * 256 + tid, r = idx >> 2, c = idx & 3;
            *(s8v*)&As[r][c * 8] = *(const s8v*)&A[(size_t)(m0 + r) * K + k0 + c * 8];
            *(s8v*)&Bs[r][c * 8] = *(const s8v*)&BT[(size_t)(n0 + r) * K + k0 + c * 8];
        }
        __syncthreads();
        bf8 af[4], bfr[4];
        #pragma unroll
        for (int i = 0; i < 4; i++) af[i] = *(const bf8*)&As[wr * 64 + i * 16 + l16][quad * 8];
        #pragma unroll
        for (int j = 0; j < 4; j++) bfr[j] = *(const bf8*)&Bs[wc * 64 + j * 16 + l16][quad * 8];
        #pragma unroll
        for (int i = 0; i < 4; i++)
            #pragma unroll
            for (int j = 0; j < 4; j++)
                acc[i][j] = __builtin_amdgcn_mfma_f32_16x16x32_bf16(af[i], bfr[j], acc[i][j], 0, 0, 0);
    }

    #pragma unroll
    for (int i = 0; i < 4; i++)
        #pragma unroll
        for (int j = 0; j < 4; j++) {
            int row0 = m0 + wr * 64 + i * 16 + quad * 4;
            int col = n0 + wc * 64 + j * 16 + l16;
            float bia = bias ? bias[col] : 0.0f;
            int jj = col & 1023, g = col >> 10;
            #pragma unroll
            for (int r = 0; r < 4; r++) {
                float v = acc[i][j][r] + bia;
                int rw = row0 + r;
                if (mode == 0) {
                    out[(size_t)rw * Nn + col] = f2bf(v);
                } else if (mode == 1) {
                    int n = rw >> 4, l = rw & 15;
                    out[(((size_t)n * 1024 + jj) * 4 + g) * 16 + l] = f2bf(v);
                } else {
                    int n = rw >> 7, t = rw & 127;
                    out[(((size_t)t * 64 + n) * 1024 + jj) * 4 + g] = f2bf(v);
                }
            }
        }
}

// ---------------- persistent recurrent kernel ----------------
// 256 wgs x 512 thr. wg = (R = wid>>7: 32 n-rows, C = wid&127: 8 h-cols x
// 4 gates). Loop: B1 -> phase A {w0-3 GEMM-A | w4,5 scores 0,1 | w6,7
// B-poll+stage halfB} -> B2 -> phase B {w0-3 GEMM-B+aL | w6,7 scores 2,3}
// -> B3 -> sL reduce + wE publish; wE poll + wL -> B4 -> gates+hpk -> B5
// -> tail {wave0 publish | w4-7 poll A-flags(t+1) (never own) + stage
// halfA(t+1), own cols from hpk}.
__global__ __launch_bounds__(512, 2) void k_recur(
    const unsigned short* __restrict__ Afl,
    const unsigned short* __restrict__ WhT, const unsigned short* __restrict__ xwx,
    const unsigned short* __restrict__ P2, const float* __restrict__ cstate,
    unsigned short* __restrict__ ring,   // [32][64][1024] bf16
    ull* __restrict__ wE,                // [64][16] epoch-tagged w
    int* __restrict__ hflag,
    float* __restrict__ out) {
    __shared__ unsigned short WhS[32][1024];       // 64 KB, persistent, swizzled
    __shared__ unsigned short hS[32][1024];        // 64 KB, per-step, swizzled
    __shared__ float aL[32][36];                   // 4.6 KB
    __shared__ float wL[512];                      // 2 KB  (32 n x 16 l)
    __shared__ float sL[4][16];                    // 256 B score partials
    __shared__ __align__(16) unsigned short hpk[32][8];  // 0.5 KB

    const int wid = blockIdx.x;               // 0..255
    const int R = wid >> 7, C = wid & 127;
    const int tid = threadIdx.x, lane = tid & 63, wave = tid >> 6;
    const int l16 = lane & 15, quad = lane >> 4;

    // GEMM tile assignment (waves 0..3)
    const int ntile = wave & 1, ctile = (wave >> 1) & 1;
    // epilogue/gate mapping (tid<256): (n_l, j)
    const int n_l = tid >> 3, j = tid & 7;
    const int n_glob = R * 32 + n_l;
    const int jcol = C * 8 + j;
    // score duty: wg (R, C<32) computes row sn = R*32 + C
    const int sn = R * 32 + C;

    // ---- load Wh slice into LDS once (rows al=q*8+jj -> acol q*1024+C*8+jj)
    for (int c = tid; c < 4096; c += 512) {    // 16B chunks
        int row = c >> 7, pos = c & 127;
        int q = row >> 3, jj = row & 7;
        int acolg = q * 1024 + C * 8 + jj;
        s8v v = *(const s8v*)&WhT[(size_t)acolg * 1024 + pos * 8];
        int e = (pos * 8) ^ ((row & 7) << 3);
        *(s8v*)&WhS[row][e] = v;
    }
    // ---- prologue: stage FULL hS(0) from ring slot 0 (k_init preceded) ----
    for (int c = tid; c < 4096; c += 512) {
        int row = c >> 7, pos = c & 127;
        s8v v = *(const s8v*)&ring[((size_t)(R * 32 + row)) * 1024 + pos * 8];
        int e = (pos * 8) ^ ((row & 7) << 3);
        *(s8v*)&hS[row][e] = v;
    }

    float creg = (tid < 256) ? cstate[(size_t)n_glob * 1024 + jcol] : 0.f;

    __syncthreads();

    for (int t = 0; t < Tt; ++t) {
        const unsigned short* rg = ring + (size_t)(t & (RING_D - 1)) * 65536;
        unsigned short* rw = ring + (size_t)((t + 1) & (RING_D - 1)) * 65536;

        // ---- prefetch epilogue operands (1x8B NT + 4x32B cached) ----
        ull xw8 = 0;
        s8v p2r[4][2];
        if (tid < 256) {
            xw8 = __builtin_nontemporal_load(
                (const ull*)xwx + ((size_t)t * 64 + n_glob) * 1024 + jcol);
            const s8v* pp = (const s8v*)(P2 + ((size_t)n_glob * 1024 + jcol) * 64);
            #pragma unroll
            for (int q = 0; q < 4; q++) {
                p2r[q][0] = pp[q * 2];
                p2r[q][1] = pp[q * 2 + 1];
            }
        }

        __syncthreads();   // B1: halfA(t) staged (prev tail / prologue)

        // ================ PHASE A ================
        f4 acc = {0.f, 0.f, 0.f, 0.f};
        const int arow = ntile * 16 + l16;
        const int brow = ctile * 16 + l16;
        const int aswz = (arow & 7) << 3, bswz = (brow & 7) << 3;
        const int kb = quad * 8;
        if (wave < 4) {
            // GEMM-A: ks 0..15 (k 0..511)
            #pragma unroll 8
            for (int ks = 0; ks < 16; ++ks) {
                bf8 a = *(const bf8*)&hS[arow][(kb + ks * 32) ^ aswz];
                bf8 b = *(const bf8*)&WhS[brow][(kb + ks * 32) ^ bswz];
                acc = __builtin_amdgcn_mfma_f32_16x16x32_bf16(a, b, acc, 0, 0, 0);
            }
        } else if (wave >= 6) {
            // waves 6,7: B-flag poll (producers C 64..127) + stage halfB(t)
            if (t > 0) {
                while (aldi(&hflag[(R * 128 + 64 + lane) * 32]) < t)
                    __builtin_amdgcn_s_sleep(2);
                __builtin_amdgcn_fence(__ATOMIC_ACQUIRE, "workgroup");
                const int tb = (wave - 6) * 64 + lane;   // 0..127
                #pragma unroll
                for (int it = 0; it < 16; ++it) {
                    int c2 = it * 128 + tb;              // 16B chunk 0..2047
                    int row = c2 >> 6, pos = 64 + (c2 & 63);   // pos 64..127
                    s8v v = *(const s8v*)&rg[((size_t)(R * 32 + row)) * 1024 + pos * 8];
                    int e = (pos * 8) ^ ((row & 7) << 3);
                    *(s8v*)&hS[row][e] = v;
                }
            }
        } else if (C < 32) {
            // waves 4,5: score partials for row C, k-ranges 0,1 (halfA)
            const int skg = wave - 4;                  // 0 or 1
            const int sl = lane & 15, kq = lane >> 4;  // l, 64-k subrange
            const int swz = (C & 7) << 3;
            const unsigned short* ap = Afl + ((size_t)sn * 16 + sl) * 1024
                                       + skg * 256 + kq * 64;
            float psum = 0.f;
            #pragma unroll
            for (int kc = 0; kc < 8; ++kc) {
                int kbase = skg * 256 + kq * 64 + kc * 8;
                s8v hv = *(const s8v*)&hS[C][kbase ^ swz];
                s8v av = *(const s8v*)&ap[kc * 8];
                #pragma unroll
                for (int e2 = 0; e2 < 8; e2++)
                    psum = fmaf(bf2f((unsigned short)hv[e2]),
                                bf2f((unsigned short)av[e2]), psum);
            }
            psum += __shfl_xor(psum, 16, 64);
            psum += __shfl_xor(psum, 32, 64);
            if (lane < 16) sL[skg][sl] = psum;
        }
        __syncthreads();   // B2: halfB staged; GEMM-A done; sL[0,1]

        // ================ PHASE B ================
        if (wave < 4) {
            // GEMM-B: ks 16..31 (k 512..1023)
            #pragma unroll 8
            for (int ks = 16; ks < 32; ++ks) {
                bf8 a = *(const bf8*)&hS[arow][(kb + ks * 32) ^ aswz];
                bf8 b = *(const bf8*)&WhS[brow][(kb + ks * 32) ^ bswz];
                acc = __builtin_amdgcn_mfma_f32_16x16x32_bf16(a, b, acc, 0, 0, 0);
            }
            #pragma unroll
            for (int r = 0; r < 4; r++)
                aL[ntile * 16 + quad * 4 + r][ctile * 16 + l16] = acc[r];
        } else if (wave >= 6 && C < 32) {
            // waves 6,7: score partials for row C, k-ranges 2,3 (halfB)
            const int skg = wave - 4;                  // 2 or 3
            const int sl = lane & 15, kq = lane >> 4;
            const int swz = (C & 7) << 3;
            const unsigned short* ap = Afl + ((size_t)sn * 16 + sl) * 1024
                                       + skg * 256 + kq * 64;
            float psum = 0.f;
            #pragma unroll
            for (int kc = 0; kc < 8; ++kc) {
                int kbase = skg * 256 + kq * 64 + kc * 8;
                s8v hv = *(const s8v*)&hS[C][kbase ^ swz];
                s8v av = *(const s8v*)&ap[kc * 8];
                #pragma unroll
                for (int e2 = 0; e2 < 8; e2++)
                    psum = fmaf(bf2f((unsigned short)hv[e2]),
                                bf2f((unsigned short)av[e2]), psum);
            }
            psum += __shfl_xor(psum, 16, 64);
            psum += __shfl_xor(psum, 32, 64);
            if (lane < 16) sL[skg][sl] = psum;
        }
        __syncthreads();   // B3: aL + sL ready

        // ---- score wgs: reduce partials, softmax, publish epoch-tagged w ----
        if (C < 32 && tid < 16) {
            float s = (sL[0][tid] + sL[1][tid] + sL[2][tid] + sL[3][tid])
                      * (1.0f / 32.0f);
            float m = s;
            m = fmaxf(m, __shfl_xor(m, 1, 64));
            m = fmaxf(m, __shfl_xor(m, 2, 64));
            m = fmaxf(m, __shfl_xor(m, 4, 64));
            m = fmaxf(m, __shfl_xor(m, 8, 64));
            float e = __expf(s - m);
            float sum = e;
            sum += __shfl_xor(sum, 1, 64);
            sum += __shfl_xor(sum, 2, 64);
            sum += __shfl_xor(sum, 4, 64);
            sum += __shfl_xor(sum, 8, 64);
            union { ull u; unsigned v[2]; } pk;
            union { float f; unsigned b; } wb; wb.f = e / sum;
            pk.v[0] = wb.b;
            pk.v[1] = (unsigned)(t + 1);
            ast(&wE[(size_t)sn * 16 + tid], pk.u);
        }

        // ---- w: poll epoch-tagged words directly (publish precedes poll) ----
        if (tid < 256) {
            const size_t wb = (size_t)n_glob * 16 + j * 2;
            ull a0, a1;
            for (;;) {
                a0 = ald(&wE[wb]);
                a1 = ald(&wE[wb + 1]);
                if ((unsigned)(a0 >> 32) >= (unsigned)(t + 1) &&
                    (unsigned)(a1 >> 32) >= (unsigned)(t + 1)) break;
                __builtin_amdgcn_s_sleep(2);
            }
            union { unsigned b; float f; } w0, w1;
            w0.b = (unsigned)a0; w1.b = (unsigned)a1;
            wL[tid * 2] = w0.f; wL[tid * 2 + 1] = w1.f;
        }
        __syncthreads();   // B4

        // ---- epilogue + gates (tid<256): thread owns (n_glob, jcol) ----
        if (tid < 256) {
            float av4[4];
            #pragma unroll
            for (int q = 0; q < 4; q++) {
                float v = aL[n_l][q * 8 + j] + bf2f((unsigned short)(xw8 >> (16 * q)));
                float sa = 0.f;
                #pragma unroll
                for (int l = 0; l < 8; l++)
                    sa = fmaf(wL[n_l * 16 + l], bf2f((unsigned short)p2r[q][0][l]), sa);
                #pragma unroll
                for (int l = 0; l < 8; l++)
                    sa = fmaf(wL[n_l * 16 + 8 + l], bf2f((unsigned short)p2r[q][1][l]), sa);
                av4[q] = v + sa;
            }
            float ig = 1.f / (1.f + __expf(-av4[0]));
            float fg = 1.f / (1.f + __expf(-av4[1]));
            float og = 1.f / (1.f + __expf(-av4[2]));
            float gg = tanhf(av4[3]);
            creg = fg * creg + ig * gg;
            float hv = og * tanhf(creg);
            out[((size_t)n_glob * Tt + t) * 1024 + jcol] = hv;
            hpk[n_l][j] = f2bf(hv);
        }
        __syncthreads();   // B5: hpk complete, visible to all waves

        // ---- tail: wave0 publish || waves 4-7 stage halfA(t+1) ----
        if (t < Tt - 1) {
            if (tid < 64) {
                // wave 0: ring stores + wave-scoped drain + flag
                int row = tid >> 1, half = tid & 1;
                ull v = *(const ull*)&hpk[row][half * 4];
                ast((ull*)rw + ((size_t)(R * 32 + row) << 8) + C * 2 + half, v);
                asm volatile("s_waitcnt vmcnt(0)" ::: "memory");
                if (tid == 0) asti(&hflag[wid * 32], t + 1);
            } else if (wave >= 4) {
                // waves 4-7: poll A-flags(t+1), NEVER own flag (own cols
                // substituted from hpk); stage halfA(t+1) into hS.
                if (!(C < 64 && lane == C)) {
                    while (aldi(&hflag[(R * 128 + lane) * 32]) < t + 1)
                        __builtin_amdgcn_s_sleep(2);
                }
                __builtin_amdgcn_fence(__ATOMIC_ACQUIRE, "workgroup");
                const int tb2 = tid - 256;               // 0..255
                #pragma unroll
                for (int it = 0; it < 8; ++it) {
                    int c2 = it * 256 + tb2;             // 16B chunk 0..2047
                    int row = c2 >> 6, pos = c2 & 63;    // pos 0..63
                    s8v v;
                    if (C < 64 && pos == C)
                        v = *(const s8v*)&hpk[row][0];   // own h(t+1) cols
                    else
                        v = *(const s8v*)&rw[((size_t)(R * 32 + row)) * 1024 + pos * 8];
                    int e = (pos * 8) ^ ((row & 7) << 3);
                    *(s8v*)&hS[row][e] = v;
                }
            }
        }
    }
}

// ---------------- launch ----------------

extern "C" void kernel_launch(void* const* d_in, const int* in_sizes, int n_in,
                              void* d_out, int out_size, void* d_ws, size_t ws_size,
                              hipStream_t stream) {
    const float* x     = (const float*)d_in[0];   // [64][128][512]
    const float* A     = (const float*)d_in[1];   // [64][1024][16]
    const float* Wx    = (const float*)d_in[2];   // [512][4096]
    const float* Wh    = (const float*)d_in[3];   // [1024][4096]
    const float* Wattn = (const float*)d_in[4];   // [1024][4096]
    const float* b     = (const float*)d_in[5];   // [4096]
    float* out = (float*)d_out;
    char* ws = (char*)d_ws;

    unsigned short* xbf    = (unsigned short*)(ws);                // 8 MB; reused for P2
    unsigned short* P2     = (unsigned short*)(ws);                // alias (xbf dead by then)
    unsigned short* WxT    = (unsigned short*)(ws + 8388608);      // 4 MB
    unsigned short* WhT    = (unsigned short*)(ws + 12582912);     // 8 MB
    unsigned short* WattnT = (unsigned short*)(ws + 20971520);     // 8 MB (dead after P2 gemm)
    unsigned short* ring   = (unsigned short*)(ws + 20971520);     // 4 MB ring, over dead WattnT
    unsigned short* Afl    = (unsigned short*)(ws + 29360128);     // 2 MB
    unsigned short* xwx    = (unsigned short*)(ws + 31457280);     // 64 MB ([t][n][j][g])
    float* cstate          = (float*)(ws + 98566144);              // 256 KB
    ull* wE                = (ull*)(ws + 98828288);                // 8 KB epoch-tagged w
    int* hflag             = (int*)(ws + 99094528);                // 32 KB (256 lines)

    (void)hipMemsetAsync(ws + 98828288, 0, 8192, stream);          // wE epochs
    (void)hipMemsetAsync(ws + 99094528, 0, 32768, stream);         // hflag

    k_cast_bf16<<<16384, 256, 0, stream>>>(x, xbf, 4194304);
    k_transpose_bf16<<<dim3(128, 16), 256, 0, stream>>>(Wx, WxT, 512);
    k_transpose_bf16<<<dim3(128, 32), 256, 0, stream>>>(Wh, WhT, 1024);
    k_transpose_bf16<<<dim3(128, 32), 256, 0, stream>>>(Wattn, WattnT, 1024);
    k_afl<<<4096, 256, 0, stream>>>(A, Afl);

    k_gemm<<<dim3(32, 64), 256, 0, stream>>>(xbf, WxT, b, xwx, 8192, 4096, 512, 2);
    k_gemm<<<dim3(32, 8), 256, 0, stream>>>(Afl, WattnT, nullptr, P2, 1024, 4096, 1024, 1);

    // k_init AFTER the gemms: ring slot 0 lives over the (now dead) WattnT
    k_init<<<256, 256, 0, stream>>>(A, cstate, ring);

    k_recur<<<256, 512, 0, stream>>>(Afl, WhT, xwx, P2, cstate, ring, wE,
                                     hflag, out);
}

// Round 12
// 996.561 us; speedup vs baseline: 1.5000x; 1.5000x over previous
//
#include <hip/hip_runtime.h>
#include <stdint.h>

// N=64, T=128, D=512, H=1024, 4H=4096.
// R17 = R14 VERBATIM (measured best: k_recur 797us, total 1010.6us).
// R15 (wider halfB staging, +43us) and R16 (tail-overlapped halfA staging,
// +525us) both regressed and are reverted. Final structure:
//   - Wh persistent in LDS (R8); h ring depth 32, producers agent stores,
//     consumers plain cached loads (R8).
//   - xwx [t][n][j][gate] 8B-NT prefetch + P2 [n][j][gate][l] contiguous
//     prefetch (R11 diet); score duty on wgs C<32, one row each (R11).
//   - split-K pipelining (R14): poll 64 A-flags -> stage halfA (512 thr)
//     -> phase A {w0-3 GEMM-A | w4,5 scores 0,1 | w6,7 B-poll+stage halfB}
//     -> phase B {w0-3 GEMM-B+aL | w6,7 scores 2,3} -> sL reduce+softmax
//     -> epoch-tagged wE publish -> consumer poll -> epilogue+gates -> hpk
//     -> wave-0 ring publish + wave-scoped vmcnt drain + flag.
// Per-step 6.23us = latency-chain floor of this fabric (HBM 3.7%, MFMA
// 3.5% -- not a HW roofline; 3 structural attempts to cut further all
// regressed).

#define Tt 128
#define FH 4096
#define RING_D 32

typedef __bf16 bf8 __attribute__((ext_vector_type(8)));
typedef float f4 __attribute__((ext_vector_type(4)));
typedef short s8v __attribute__((ext_vector_type(8)));
typedef unsigned long long ull;

__device__ __forceinline__ float bf2f(unsigned short u) {
    union { unsigned u32; float f; } x; x.u32 = ((unsigned)u) << 16; return x.f;
}
__device__ __forceinline__ unsigned short f2bf(float f) {
    union { float f32; unsigned u; } x; x.f32 = f;
    unsigned r = x.u + 0x7fffu + ((x.u >> 16) & 1u);
    return (unsigned short)(r >> 16);
}
__device__ __forceinline__ ull ald(const ull* p) {
    return __hip_atomic_load((ull*)p, __ATOMIC_RELAXED, __HIP_MEMORY_SCOPE_AGENT);
}
__device__ __forceinline__ void ast(ull* p, ull v) {
    __hip_atomic_store(p, v, __ATOMIC_RELAXED, __HIP_MEMORY_SCOPE_AGENT);
}
__device__ __forceinline__ int aldi(const int* p) {
    return __hip_atomic_load((int*)p, __ATOMIC_RELAXED, __HIP_MEMORY_SCOPE_AGENT);
}
__device__ __forceinline__ void asti(int* p, int v) {
    __hip_atomic_store(p, v, __ATOMIC_RELAXED, __HIP_MEMORY_SCOPE_AGENT);
}

// ---------------- converts / init ----------------

__global__ __launch_bounds__(256) void k_cast_bf16(const float* __restrict__ in,
                                                   unsigned short* __restrict__ out, int n) {
    int i = blockIdx.x * 256 + threadIdx.x;
    if (i < n) out[i] = f2bf(in[i]);
}

__global__ __launch_bounds__(256) void k_transpose_bf16(const float* __restrict__ W,
                                                        unsigned short* __restrict__ WT, int K) {
    __shared__ float tl[32][33];
    int c0 = blockIdx.x * 32, k0 = blockIdx.y * 32;
    int tx = threadIdx.x & 31, ty = threadIdx.x >> 5;
    #pragma unroll
    for (int i = 0; i < 32; i += 8) tl[ty + i][tx] = W[(size_t)(k0 + ty + i) * 4096 + c0 + tx];
    __syncthreads();
    #pragma unroll
    for (int i = 0; i < 32; i += 8) WT[(size_t)(c0 + ty + i) * K + k0 + tx] = f2bf(tl[tx][ty + i]);
}

__global__ __launch_bounds__(256) void k_afl(const float* __restrict__ A,
                                             unsigned short* __restrict__ Afl) {
    int idx = blockIdx.x * 256 + threadIdx.x;
    int k = idx & 1023, l = (idx >> 10) & 15, n = idx >> 14;
    Afl[idx] = f2bf(A[((size_t)n * 1024 + k) * 16 + l]);   // Afl[n][l][k]
}

__global__ __launch_bounds__(256) void k_init(const float* __restrict__ A,
                                              float* __restrict__ cstate,
                                              unsigned short* __restrict__ ring0) {
    int idx = blockIdx.x * 256 + threadIdx.x;   // 64*1024
    const float* ap = A + (size_t)idx * 16;
    float s = 0.f;
    #pragma unroll
    for (int l = 0; l < 16; l++) s += ap[l];
    float h = s * (1.0f / 16.0f);
    cstate[idx] = h;
    ring0[idx] = f2bf(h);
}

// ---------------- generic bf16 MFMA GEMM (preamble) ----------------
// mode 0: out[row][col]
// mode 1: P2 layout [n][j(1024)][gate(4)][l(16)]   (row = n*16 + l)
// mode 2: xwx layout [t][n][j(1024)][gate(4)]      (row = n*128 + t)
__global__ __launch_bounds__(256) void k_gemm(const unsigned short* __restrict__ A,
                                              const unsigned short* __restrict__ BT,
                                              const float* __restrict__ bias,
                                              unsigned short* __restrict__ out,
                                              int M, int Nn, int K, int mode) {
    __shared__ unsigned short As[128][40];
    __shared__ unsigned short Bs[128][40];
    int m0 = blockIdx.y * 128, n0 = blockIdx.x * 128;
    int tid = threadIdx.x, lane = tid & 63, wave = tid >> 6;
    int wr = wave >> 1, wc = wave & 1, quad = lane >> 4, l16 = lane & 15;
    f4 acc[4][4];
    #pragma unroll
    for (int i = 0; i < 4; i++)
        #pragma unroll
        for (int j = 0; j < 4; j++) acc[i][j] = f4{0.f, 0.f, 0.f, 0.f};

    for (int k0 = 0; k0 < K; k0 += 32) {
        __syncthreads();
        #pragma unroll
        for (int i = 0; i < 2; i++) {
            int idx = i * 256 + tid, r = idx >> 2, c = idx & 3;
            *(s8v*)&As[r][c * 8] = *(const s8v*)&A[(size_t)(m0 + r) * K + k0 + c * 8];
            *(s8v*)&Bs[r][c * 8] = *(const s8v*)&BT[(size_t)(n0 + r) * K + k0 + c * 8];
        }
        __syncthreads();
        bf8 af[4], bfr[4];
        #pragma unroll
        for (int i = 0; i < 4; i++) af[i] = *(const bf8*)&As[wr * 64 + i * 16 + l16][quad * 8];
        #pragma unroll
        for (int j = 0; j < 4; j++) bfr[j] = *(const bf8*)&Bs[wc * 64 + j * 16 + l16][quad * 8];
        #pragma unroll
        for (int i = 0; i < 4; i++)
            #pragma unroll
            for (int j = 0; j < 4; j++)
                acc[i][j] = __builtin_amdgcn_mfma_f32_16x16x32_bf16(af[i], bfr[j], acc[i][j], 0, 0, 0);
    }

    #pragma unroll
    for (int i = 0; i < 4; i++)
        #pragma unroll
        for (int j = 0; j < 4; j++) {
            int row0 = m0 + wr * 64 + i * 16 + quad * 4;
            int col = n0 + wc * 64 + j * 16 + l16;
            float bia = bias ? bias[col] : 0.0f;
            int jj = col & 1023, g = col >> 10;
            #pragma unroll
            for (int r = 0; r < 4; r++) {
                float v = acc[i][j][r] + bia;
                int rw = row0 + r;
                if (mode == 0) {
                    out[(size_t)rw * Nn + col] = f2bf(v);
                } else if (mode == 1) {
                    int n = rw >> 4, l = rw & 15;
                    out[(((size_t)n * 1024 + jj) * 4 + g) * 16 + l] = f2bf(v);
                } else {
                    int n = rw >> 7, t = rw & 127;
                    out[(((size_t)t * 64 + n) * 1024 + jj) * 4 + g] = f2bf(v);
                }
            }
        }
}

// ---------------- persistent recurrent kernel ----------------
// 256 wgs x 512 thr. wg = (R = wid>>7: 32 n-rows, C = wid&127: 8 h-cols x
// 4 gates). Waves 0..3: GEMM (split-K, acc carried) + consumer duty.
// Waves 4,5 (C<32): score k-ranges 0,1 (phase A). Waves 6,7: B-flag poll +
// halfB staging (phase A), then (C<32) score k-ranges 2,3 (phase B).
// hflag[w*32] w=0..255 : writer wg w; A-pollers tid<64 (C 0..63),
//                        B-pollers waves 6,7 lanes (C 64..127).
// wE[64][16] ull: {f32 w | u32 epoch}, writer wg (R,C<32) tid<16;
//                 pollers: each consumer thread its own 2 words.
__global__ __launch_bounds__(512, 2) void k_recur(
    const unsigned short* __restrict__ Afl,
    const unsigned short* __restrict__ WhT, const unsigned short* __restrict__ xwx,
    const unsigned short* __restrict__ P2, const float* __restrict__ cstate,
    unsigned short* __restrict__ ring,   // [32][64][1024] bf16
    ull* __restrict__ wE,                // [64][16] epoch-tagged w
    int* __restrict__ hflag,
    float* __restrict__ out) {
    __shared__ unsigned short WhS[32][1024];   // 64 KB, persistent, swizzled
    __shared__ unsigned short hS[32][1024];    // 64 KB, per-step, swizzled
    __shared__ float aL[32][36];               // 4.6 KB
    __shared__ float wL[512];                  // 2 KB  (32 n x 16 l)
    __shared__ float sL[4][16];                // 256 B score partials
    __shared__ unsigned short hpk[32][8];      // 0.5 KB

    const int wid = blockIdx.x;               // 0..255
    const int R = wid >> 7, C = wid & 127;
    const int tid = threadIdx.x, lane = tid & 63, wave = tid >> 6;
    const int l16 = lane & 15, quad = lane >> 4;

    // GEMM tile assignment (waves 0..3)
    const int ntile = wave & 1, ctile = (wave >> 1) & 1;
    // epilogue/gate mapping (tid<256): (n_l, j)
    const int n_l = tid >> 3, j = tid & 7;
    const int n_glob = R * 32 + n_l;
    const int jcol = C * 8 + j;
    // score duty: wg (R, C<32) computes row sn = R*32 + C
    const int sn = R * 32 + C;

    // ---- load Wh slice into LDS once (rows al=q*8+jj -> acol q*1024+C*8+jj)
    for (int c = tid; c < 4096; c += 512) {    // 16B chunks
        int row = c >> 7, pos = c & 127;
        int q = row >> 3, jj = row & 7;
        int acolg = q * 1024 + C * 8 + jj;
        s8v v = *(const s8v*)&WhT[(size_t)acolg * 1024 + pos * 8];
        int e = (pos * 8) ^ ((row & 7) << 3);
        *(s8v*)&WhS[row][e] = v;
    }

    float creg = (tid < 256) ? cstate[(size_t)n_glob * 1024 + jcol] : 0.f;

    __syncthreads();

    for (int t = 0; t < Tt; ++t) {
        const unsigned short* rg = ring + (size_t)(t & (RING_D - 1)) * 65536;
        unsigned short* rw = ring + (size_t)((t + 1) & (RING_D - 1)) * 65536;

        // ---- prefetch epilogue operands (1x8B NT + 4x32B cached) ----
        ull xw8 = 0;
        s8v p2r[4][2];
        if (tid < 256) {
            xw8 = __builtin_nontemporal_load(
                (const ull*)xwx + ((size_t)t * 64 + n_glob) * 1024 + jcol);
            const s8v* pp = (const s8v*)(P2 + ((size_t)n_glob * 1024 + jcol) * 64);
            #pragma unroll
            for (int q = 0; q < 4; q++) {
                p2r[q][0] = pp[q * 2];
                p2r[q][1] = pp[q * 2 + 1];
            }
        }

        // ---- wait for h(t) A-HALF: 64 threads poll producer flags C<64 ----
        if (t > 0 && tid < 64) {
            while (aldi(&hflag[(R * 128 + tid) * 32]) < t)
                __builtin_amdgcn_s_sleep(2);
        }
        __syncthreads();
        __builtin_amdgcn_fence(__ATOMIC_ACQUIRE, "workgroup");

        // ---- stage halfA (32 rows x k 0..511) into swizzled LDS ----
        #pragma unroll
        for (int it = 0; it < 4; ++it) {
            int c = it * 512 + tid;            // 16B chunk 0..2047
            int row = c >> 6, pos = c & 63;    // pos 0..63
            s8v v = *(const s8v*)&rg[((size_t)(R * 32 + row)) * 1024 + pos * 8];
            int e = (pos * 8) ^ ((row & 7) << 3);
            *(s8v*)&hS[row][e] = v;
        }
        __syncthreads();

        // ================ PHASE A ================
        f4 acc = {0.f, 0.f, 0.f, 0.f};
        const int arow = ntile * 16 + l16;
        const int brow = ctile * 16 + l16;
        const int aswz = (arow & 7) << 3, bswz = (brow & 7) << 3;
        const int kb = quad * 8;
        if (wave < 4) {
            // GEMM-A: ks 0..15 (k 0..511)
            #pragma unroll 8
            for (int ks = 0; ks < 16; ++ks) {
                bf8 a = *(const bf8*)&hS[arow][(kb + ks * 32) ^ aswz];
                bf8 b = *(const bf8*)&WhS[brow][(kb + ks * 32) ^ bswz];
                acc = __builtin_amdgcn_mfma_f32_16x16x32_bf16(a, b, acc, 0, 0, 0);
            }
        } else if (wave >= 6) {
            // B-flag poll (producer wgs C 64..127) + stage halfB
            if (t > 0) {
                while (aldi(&hflag[(R * 128 + 64 + lane) * 32]) < t)
                    __builtin_amdgcn_s_sleep(2);
            }
            __builtin_amdgcn_fence(__ATOMIC_ACQUIRE, "workgroup");
            const int tb = (wave - 6) * 64 + lane;   // 0..127
            #pragma unroll
            for (int it = 0; it < 16; ++it) {
                int c2 = it * 128 + tb;              // 16B chunk 0..2047
                int row = c2 >> 6, pos = 64 + (c2 & 63);   // pos 64..127
                s8v v = *(const s8v*)&rg[((size_t)(R * 32 + row)) * 1024 + pos * 8];
                int e = (pos * 8) ^ ((row & 7) << 3);
                *(s8v*)&hS[row][e] = v;
            }
        } else if (C < 32) {
            // waves 4,5: score partials for row C, k-ranges 0,1 (halfA)
            const int skg = wave - 4;                  // 0 or 1
            const int sl = lane & 15, kq = lane >> 4;  // l, 64-k subrange
            const int swz = (C & 7) << 3;
            const unsigned short* ap = Afl + ((size_t)sn * 16 + sl) * 1024
                                       + skg * 256 + kq * 64;
            float psum = 0.f;
            #pragma unroll
            for (int kc = 0; kc < 8; ++kc) {
                int kbase = skg * 256 + kq * 64 + kc * 8;
                s8v hv = *(const s8v*)&hS[C][kbase ^ swz];
                s8v av = *(const s8v*)&ap[kc * 8];
                #pragma unroll
                for (int e2 = 0; e2 < 8; e2++)
                    psum = fmaf(bf2f((unsigned short)hv[e2]),
                                bf2f((unsigned short)av[e2]), psum);
            }
            psum += __shfl_xor(psum, 16, 64);
            psum += __shfl_xor(psum, 32, 64);
            if (lane < 16) sL[skg][sl] = psum;
        }
        __syncthreads();   // halfB staged; GEMM-A done; sL[0,1] written

        // ================ PHASE B ================
        if (wave < 4) {
            // GEMM-B: ks 16..31 (k 512..1023)
            #pragma unroll 8
            for (int ks = 16; ks < 32; ++ks) {
                bf8 a = *(const bf8*)&hS[arow][(kb + ks * 32) ^ aswz];
                bf8 b = *(const bf8*)&WhS[brow][(kb + ks * 32) ^ bswz];
                acc = __builtin_amdgcn_mfma_f32_16x16x32_bf16(a, b, acc, 0, 0, 0);
            }
            #pragma unroll
            for (int r = 0; r < 4; r++)
                aL[ntile * 16 + quad * 4 + r][ctile * 16 + l16] = acc[r];
        } else if (wave >= 6 && C < 32) {
            // waves 6,7: score partials for row C, k-ranges 2,3 (halfB)
            const int skg = wave - 4;                  // 2 or 3
            const int sl = lane & 15, kq = lane >> 4;
            const int swz = (C & 7) << 3;
            const unsigned short* ap = Afl + ((size_t)sn * 16 + sl) * 1024
                                       + skg * 256 + kq * 64;
            float psum = 0.f;
            #pragma unroll
            for (int kc = 0; kc < 8; ++kc) {
                int kbase = skg * 256 + kq * 64 + kc * 8;
                s8v hv = *(const s8v*)&hS[C][kbase ^ swz];
                s8v av = *(const s8v*)&ap[kc * 8];
                #pragma unroll
                for (int e2 = 0; e2 < 8; e2++)
                    psum = fmaf(bf2f((unsigned short)hv[e2]),
                                bf2f((unsigned short)av[e2]), psum);
            }
            psum += __shfl_xor(psum, 16, 64);
            psum += __shfl_xor(psum, 32, 64);
            if (lane < 16) sL[skg][sl] = psum;
        }
        __syncthreads();   // aL + sL ready

        // ---- score wgs: reduce partials, softmax, publish epoch-tagged w ----
        if (C < 32 && tid < 16) {
            float s = (sL[0][tid] + sL[1][tid] + sL[2][tid] + sL[3][tid])
                      * (1.0f / 32.0f);
            float m = s;
            m = fmaxf(m, __shfl_xor(m, 1, 64));
            m = fmaxf(m, __shfl_xor(m, 2, 64));
            m = fmaxf(m, __shfl_xor(m, 4, 64));
            m = fmaxf(m, __shfl_xor(m, 8, 64));
            float e = __expf(s - m);
            float sum = e;
            sum += __shfl_xor(sum, 1, 64);
            sum += __shfl_xor(sum, 2, 64);
            sum += __shfl_xor(sum, 4, 64);
            sum += __shfl_xor(sum, 8, 64);
            union { ull u; unsigned v[2]; } pk;
            union { float f; unsigned b; } wb; wb.f = e / sum;
            pk.v[0] = wb.b;
            pk.v[1] = (unsigned)(t + 1);
            ast(&wE[(size_t)sn * 16 + tid], pk.u);
        }

        // ---- w: poll epoch-tagged words directly (publish precedes poll) ----
        if (tid < 256) {
            const size_t wb = (size_t)n_glob * 16 + j * 2;
            ull a0, a1;
            for (;;) {
                a0 = ald(&wE[wb]);
                a1 = ald(&wE[wb + 1]);
                if ((unsigned)(a0 >> 32) >= (unsigned)(t + 1) &&
                    (unsigned)(a1 >> 32) >= (unsigned)(t + 1)) break;
                __builtin_amdgcn_s_sleep(2);
            }
            union { unsigned b; float f; } w0, w1;
            w0.b = (unsigned)a0; w1.b = (unsigned)a1;
            wL[tid * 2] = w0.f; wL[tid * 2 + 1] = w1.f;
        }
        __syncthreads();

        // ---- epilogue + gates (tid<256): thread owns (n_glob, jcol) ----
        if (tid < 256) {
            float av4[4];
            #pragma unroll
            for (int q = 0; q < 4; q++) {
                float v = aL[n_l][q * 8 + j] + bf2f((unsigned short)(xw8 >> (16 * q)));
                float sa = 0.f;
                #pragma unroll
                for (int l = 0; l < 8; l++)
                    sa = fmaf(wL[n_l * 16 + l], bf2f((unsigned short)p2r[q][0][l]), sa);
                #pragma unroll
                for (int l = 0; l < 8; l++)
                    sa = fmaf(wL[n_l * 16 + 8 + l], bf2f((unsigned short)p2r[q][1][l]), sa);
                av4[q] = v + sa;
            }
            float ig = 1.f / (1.f + __expf(-av4[0]));
            float fg = 1.f / (1.f + __expf(-av4[1]));
            float og = 1.f / (1.f + __expf(-av4[2]));
            float gg = tanhf(av4[3]);
            creg = fg * creg + ig * gg;
            float hv = og * tanhf(creg);
            out[((size_t)n_glob * Tt + t) * 1024 + jcol] = hv;
            hpk[n_l][j] = f2bf(hv);
        }
        __syncthreads();   // hpk complete, visible to wave 0

        // ---- wave-0 fast publish: ring stores + wave-scoped drain + flag ----
        if (t < Tt - 1) {
            if (tid < 64) {
                int row = tid >> 1, half = tid & 1;
                ull v = *(const ull*)&hpk[row][half * 4];
                ast((ull*)rw + ((size_t)(R * 32 + row) << 8) + C * 2 + half, v);
                asm volatile("s_waitcnt vmcnt(0)" ::: "memory");
                if (tid == 0) asti(&hflag[wid * 32], t + 1);
            }
        }
    }
}

// ---------------- launch ----------------

extern "C" void kernel_launch(void* const* d_in, const int* in_sizes, int n_in,
                              void* d_out, int out_size, void* d_ws, size_t ws_size,
                              hipStream_t stream) {
    const float* x     = (const float*)d_in[0];   // [64][128][512]
    const float* A     = (const float*)d_in[1];   // [64][1024][16]
    const float* Wx    = (const float*)d_in[2];   // [512][4096]
    const float* Wh    = (const float*)d_in[3];   // [1024][4096]
    const float* Wattn = (const float*)d_in[4];   // [1024][4096]
    const float* b     = (const float*)d_in[5];   // [4096]
    float* out = (float*)d_out;
    char* ws = (char*)d_ws;

    unsigned short* xbf    = (unsigned short*)(ws);                // 8 MB; reused for P2
    unsigned short* P2     = (unsigned short*)(ws);                // alias (xbf dead by then)
    unsigned short* WxT    = (unsigned short*)(ws + 8388608);      // 4 MB
    unsigned short* WhT    = (unsigned short*)(ws + 12582912);     // 8 MB
    unsigned short* WattnT = (unsigned short*)(ws + 20971520);     // 8 MB (dead after P2 gemm)
    unsigned short* ring   = (unsigned short*)(ws + 20971520);     // 4 MB ring, over dead WattnT
    unsigned short* Afl    = (unsigned short*)(ws + 29360128);     // 2 MB
    unsigned short* xwx    = (unsigned short*)(ws + 31457280);     // 64 MB ([t][n][j][g])
    float* cstate          = (float*)(ws + 98566144);              // 256 KB
    ull* wE                = (ull*)(ws + 98828288);                // 8 KB epoch-tagged w
    int* hflag             = (int*)(ws + 99094528);                // 32 KB (256 lines)

    (void)hipMemsetAsync(ws + 98828288, 0, 8192, stream);          // wE epochs
    (void)hipMemsetAsync(ws + 99094528, 0, 32768, stream);         // hflag

    k_cast_bf16<<<16384, 256, 0, stream>>>(x, xbf, 4194304);
    k_transpose_bf16<<<dim3(128, 16), 256, 0, stream>>>(Wx, WxT, 512);
    k_transpose_bf16<<<dim3(128, 32), 256, 0, stream>>>(Wh, WhT, 1024);
    k_transpose_bf16<<<dim3(128, 32), 256, 0, stream>>>(Wattn, WattnT, 1024);
    k_afl<<<4096, 256, 0, stream>>>(A, Afl);

    k_gemm<<<dim3(32, 64), 256, 0, stream>>>(xbf, WxT, b, xwx, 8192, 4096, 512, 2);
    k_gemm<<<dim3(32, 8), 256, 0, stream>>>(Afl, WattnT, nullptr, P2, 1024, 4096, 1024, 1);

    // k_init AFTER the gemms: ring slot 0 lives over the (now dead) WattnT
    k_init<<<256, 256, 0, stream>>>(A, cstate, ring);

    k_recur<<<256, 512, 0, stream>>>(Afl, WhT, xwx, P2, cstate, ring, wE,
                                     hflag, out);
}